// Round 4
// baseline (102.329 us; speedup 1.0000x reference)
//
#include <hip/hip_runtime.h>

#define NGRAPH 512
#define DF 96
#define DHID 10
#define NCHUNK 256
#define HTHREADS 1024
#define ATHREADS 1024

// ---------------------------------------------------------------------------
// Kernel A: per-chunk histogram over graph ids + cache g per edge.
// Writes TRANSPOSED: histT[g*NCHUNK + c] so scan reads are contiguous per g.
// ---------------------------------------------------------------------------
__global__ __launch_bounds__(HTHREADS) void hist_kernel(
    const int* __restrict__ edge_index,      // [2*E]
    const int* __restrict__ batch,           // [N]
    int E, int chunk,
    int* __restrict__ histT,                 // [NGRAPH*NCHUNK]
    unsigned short* __restrict__ g16)        // [E]
{
    __shared__ int lh[NGRAPH];
    for (int i = threadIdx.x; i < NGRAPH; i += HTHREADS) lh[i] = 0;
    __syncthreads();

    const int* __restrict__ dst = edge_index + E;
    const int lo = blockIdx.x * chunk;
    const int hi = min(E, lo + chunk);
    for (int e = lo + threadIdx.x; e < hi; e += HTHREADS) {
        const int g = batch[dst[e]];
        g16[e] = (unsigned short)g;
        atomicAdd(&lh[g], 1);
    }
    __syncthreads();
    for (int i = threadIdx.x; i < NGRAPH; i += HTHREADS)
        histT[i * NCHUNK + blockIdx.x] = lh[i];
}

// ---------------------------------------------------------------------------
// Kernel B: one block, 1024 threads.
// Phase 1: wave w scans graphs g = w, w+16, ... : inclusive shuffle-scan of
//   the 256 chunk counts (int4 per lane), writes EXCLUSIVE prefix back into
//   baseT[g*NCHUNK+c] (relative, no global offset) and total -> LDS.
// Phase 2: 512-wide LDS scan of totals -> off[g] (exclusive).
// ---------------------------------------------------------------------------
__global__ __launch_bounds__(1024) void scan_kernel(
    const int* __restrict__ histT,    // [NGRAPH*NCHUNK]
    int* __restrict__ baseT,          // [NGRAPH*NCHUNK] relative prefixes
    int* __restrict__ off,            // [NGRAPH+1]
    int E)
{
    __shared__ int tot[NGRAPH];
    const int t    = threadIdx.x;
    const int wave = t >> 6;
    const int lane = t & 63;

    for (int g = wave; g < NGRAPH; g += 16) {
        const int4 v = ((const int4*)(histT + g * NCHUNK))[lane];
        const int s0 = v.x;
        const int s1 = s0 + v.y;
        const int s2 = s1 + v.z;
        const int s3 = s2 + v.w;
        int p = s3;
        #pragma unroll
        for (int d = 1; d < 64; d <<= 1) {
            const int u = __shfl_up(p, d, 64);
            if (lane >= d) p += u;
        }
        const int base = p - s3;            // exclusive across lanes
        int4 o;
        o.x = base;
        o.y = base + s0;
        o.z = base + s1;
        o.w = base + s2;
        ((int4*)(baseT + g * NCHUNK))[lane] = o;
        const int total = __shfl(p, 63, 64);
        if (lane == 0) tot[g] = total;
    }
    __syncthreads();

    // 512-wide Hillis-Steele scan (all 1024 threads hit the barriers)
    for (int d = 1; d < NGRAPH; d <<= 1) {
        int add = 0;
        if (t < NGRAPH && t >= d) add = tot[t - d];
        __syncthreads();
        if (t < NGRAPH) tot[t] += add;
        __syncthreads();
    }
    if (t < NGRAPH) {
        // tot[t] is inclusive; recompute exclusive via neighbor
        const int incl = tot[t];
        off[t + 1] = incl;                  // off[g+1] = inclusive sum
        if (t == 0) off[0] = 0;
    }
}

// ---------------------------------------------------------------------------
// Kernel C: scatter into graph-contiguous order. LDS cursors only.
// cursor[g] = off[g] + baseT[g][chunk]
// ---------------------------------------------------------------------------
__global__ __launch_bounds__(HTHREADS) void scatter_kernel(
    const int* __restrict__ edge_index,
    const float* __restrict__ edge_attr,
    const unsigned short* __restrict__ g16,
    const int* __restrict__ baseT,
    const int* __restrict__ off,
    int E, int chunk,
    int2* __restrict__ ed)            // [E] packed (src, w)
{
    __shared__ int lcur[NGRAPH];
    for (int i = threadIdx.x; i < NGRAPH; i += HTHREADS)
        lcur[i] = off[i] + baseT[i * NCHUNK + blockIdx.x];
    __syncthreads();

    const int lo = blockIdx.x * chunk;
    const int hi = min(E, lo + chunk);
    for (int e = lo + threadIdx.x; e < hi; e += HTHREADS) {
        const int g = g16[e];
        const int p = atomicAdd(&lcur[g], 1);
        ed[p] = make_int2(edge_index[e], __float_as_int(edge_attr[e]));
    }
}

// ---------------------------------------------------------------------------
// Kernel D: per-graph gather + register-accumulate. 1024 threads (16 waves),
// 8 edge-groups x 8 feature-lanes per wave; 128 edges in flight per block.
// ---------------------------------------------------------------------------
__global__ __launch_bounds__(ATHREADS) void aggregate_kernel(
    const int2* __restrict__ ed,
    const int* __restrict__ off,
    const float* __restrict__ x,     // [N*DF]
    float* __restrict__ sums)        // [NGRAPH*DF]
{
    const int g     = blockIdx.x;
    const int start = off[g];
    const int end   = off[g + 1];
    const int wave  = threadIdx.x >> 6;
    const int lane  = threadIdx.x & 63;
    const int eg    = lane >> 3;
    const int fc    = lane & 7;

    float acc[12];
#pragma unroll
    for (int i = 0; i < 12; ++i) acc[i] = 0.f;

    int e = start + wave * 8 + eg;
    int2 sw = (e < end) ? ed[e] : make_int2(0, 0);
    while (e < end) {
        const int en = e + (ATHREADS / 8);
        const int2 swn = (en < end) ? ed[en] : make_int2(0, 0);

        const float w = __int_as_float(sw.y);
        const float4* __restrict__ row = (const float4*)x + (size_t)sw.x * 24;
#pragma unroll
        for (int c = 0; c < 3; ++c) {
            const float4 v = row[fc + c * 8];
            acc[c * 4 + 0] += w * v.x;
            acc[c * 4 + 1] += w * v.y;
            acc[c * 4 + 2] += w * v.z;
            acc[c * 4 + 3] += w * v.w;
        }
        e = en; sw = swn;
    }

#pragma unroll
    for (int m = 8; m <= 32; m <<= 1) {
#pragma unroll
        for (int i = 0; i < 12; ++i) acc[i] += __shfl_xor(acc[i], m, 64);
    }

    __shared__ float sh[ATHREADS / 64][DF];
    if (eg == 0) {
#pragma unroll
        for (int c = 0; c < 3; ++c)
#pragma unroll
            for (int k = 0; k < 4; ++k)
                sh[wave][c * 32 + fc * 4 + k] = acc[c * 4 + k];
    }
    __syncthreads();
    if (threadIdx.x < DF) {
        float s = 0.f;
#pragma unroll
        for (int wv = 0; wv < ATHREADS / 64; ++wv) s += sh[wv][threadIdx.x];
        sums[g * DF + threadIdx.x] = s;
    }
}

// ---------------------------------------------------------------------------
// Kernel E: mean-pool (counts via binary search on sorted batch) + MLP head.
// ---------------------------------------------------------------------------
__global__ __launch_bounds__(NGRAPH) void finish_kernel(
    const float* __restrict__ sums,
    const int* __restrict__ batch,
    int nNodes,
    const float* __restrict__ W1,
    const float* __restrict__ b1,
    const float* __restrict__ W2,
    const float* __restrict__ b2,
    float* __restrict__ out)
{
    __shared__ float sW1[DF * DHID];
    __shared__ float sb1[DHID];
    __shared__ float sW2[DHID];
    const int t = threadIdx.x;
    for (int i = t; i < DF * DHID; i += blockDim.x) sW1[i] = W1[i];
    if (t < DHID) { sb1[t] = b1[t]; sW2[t] = W2[t]; }
    __syncthreads();

    const int g = t;
    int lo = 0, hi = nNodes;
    while (lo < hi) { int m = (lo + hi) >> 1; if (batch[m] < g) lo = m + 1; else hi = m; }
    const int lb = lo;
    hi = nNodes;
    while (lo < hi) { int m = (lo + hi) >> 1; if (batch[m] <= g) lo = m + 1; else hi = m; }
    const int cnt = lo - lb;
    const float inv = 1.f / fmaxf((float)cnt, 1.f);

    float hid[DHID];
#pragma unroll
    for (int j = 0; j < DHID; ++j) hid[j] = sb1[j];

    for (int f = 0; f < DF; ++f) {
        const float z = fmaxf(sums[g * DF + f] * inv, 0.f);
#pragma unroll
        for (int j = 0; j < DHID; ++j) hid[j] += z * sW1[f * DHID + j];
    }

    float o = b2[0];
#pragma unroll
    for (int j = 0; j < DHID; ++j) o += fmaxf(hid[j], 0.f) * sW2[j];
    out[g] = o;
}

// ---------------------------------------------------------------------------
extern "C" void kernel_launch(void* const* d_in, const int* in_sizes, int n_in,
                              void* d_out, int out_size, void* d_ws, size_t ws_size,
                              hipStream_t stream) {
    const float* x          = (const float*)d_in[0];
    const int*   edge_index = (const int*)  d_in[1];
    const float* edge_attr  = (const float*)d_in[2];
    const int*   batch      = (const int*)  d_in[3];
    const float* W1         = (const float*)d_in[4];
    const float* b1         = (const float*)d_in[5];
    const float* W2         = (const float*)d_in[6];
    const float* b2         = (const float*)d_in[7];

    const int E = in_sizes[1] / 2;   // 800000
    const int N = in_sizes[3];       // 50000
    const int chunk = (E + NCHUNK - 1) / NCHUNK;

    // workspace layout
    char* ws = (char*)d_ws;
    int2*           ed   = (int2*)ws;                                // 8*E bytes
    unsigned short* g16  = (unsigned short*)(ws + (size_t)8 * E);    // 2*E
    char* tail = ws + (size_t)10 * E;
    tail = (char*)(((size_t)tail + 255) & ~(size_t)255);
    int*   histT = (int*)tail;                        // NGRAPH*NCHUNK
    int*   baseT = histT + NGRAPH * NCHUNK;           // NGRAPH*NCHUNK
    int*   off   = baseT + NGRAPH * NCHUNK;           // NGRAPH+1
    float* sums  = (float*)(off + NGRAPH + 2);        // NGRAPH*DF

    hist_kernel<<<NCHUNK, HTHREADS, 0, stream>>>(edge_index, batch, E, chunk,
                                                 histT, g16);
    scan_kernel<<<1, 1024, 0, stream>>>(histT, baseT, off, E);
    scatter_kernel<<<NCHUNK, HTHREADS, 0, stream>>>(edge_index, edge_attr, g16,
                                                    baseT, off, E, chunk, ed);
    aggregate_kernel<<<NGRAPH, ATHREADS, 0, stream>>>(ed, off, x, sums);
    finish_kernel<<<1, NGRAPH, 0, stream>>>(sums, batch, N, W1, b1, W2, b2,
                                            (float*)d_out);
}

// Round 5
// 80.952 us; speedup vs baseline: 1.2641x; 1.2641x over previous
//
#include <hip/hip_runtime.h>

#define NGRAPH 512
#define DF 96
#define DHID 10
#define NCHUNK 256
#define HTHREADS 1024
#define ATHREADS 1024

// bf16 round-to-nearest-even
static __device__ __forceinline__ unsigned short f2bf(float f) {
    unsigned int u = __float_as_uint(f);
    u = (u + 0x7fffu + ((u >> 16) & 1u)) >> 16;
    return (unsigned short)u;
}
static __device__ __forceinline__ float bf2f(unsigned short s) {
    return __uint_as_float(((unsigned int)s) << 16);
}

// ---------------------------------------------------------------------------
// Kernel A (prep): x -> bf16 convert, node-count histogram, per-chunk edge
// histogram (transposed) + cached graph id per edge.
// ---------------------------------------------------------------------------
__global__ __launch_bounds__(HTHREADS) void prep_kernel(
    const int* __restrict__ edge_index,      // [2*E]
    const int* __restrict__ batch,           // [N] sorted
    const float* __restrict__ x,             // [N*DF]
    int E, int N, int echunk, int nchunk,
    int* __restrict__ histT,                 // [NGRAPH*NCHUNK]
    unsigned short* __restrict__ g16,        // [E]
    unsigned short* __restrict__ xb,         // [N*DF] bf16
    int* __restrict__ cnt)                   // [NGRAPH] pre-zeroed
{
    // --- x -> bf16 (grid-stride, independent of the rest) ---
    const int nf4 = N * DF / 4;
    for (int i = blockIdx.x * HTHREADS + threadIdx.x; i < nf4;
         i += gridDim.x * HTHREADS) {
        const float4 v = ((const float4*)x)[i];
        ushort4 o;
        o.x = f2bf(v.x); o.y = f2bf(v.y); o.z = f2bf(v.z); o.w = f2bf(v.w);
        ((ushort4*)xb)[i] = o;
    }

    __shared__ int lh[NGRAPH];   // edge hist
    __shared__ int lc[NGRAPH];   // node hist
    for (int i = threadIdx.x; i < NGRAPH; i += HTHREADS) { lh[i] = 0; lc[i] = 0; }
    __syncthreads();

    // --- node counts (batch sorted -> ~2 hot bins per block, cheap) ---
    {
        const int lo = blockIdx.x * nchunk;
        const int hi = min(N, lo + nchunk);
        for (int i = lo + threadIdx.x; i < hi; i += HTHREADS)
            atomicAdd(&lc[batch[i]], 1);
    }

    // --- edge hist + g16 cache ---
    const int* __restrict__ dst = edge_index + E;
    const int lo = blockIdx.x * echunk;
    const int hi = min(E, lo + echunk);
    for (int e = lo + threadIdx.x; e < hi; e += HTHREADS) {
        const int g = batch[dst[e]];
        g16[e] = (unsigned short)g;
        atomicAdd(&lh[g], 1);
    }
    __syncthreads();

    for (int i = threadIdx.x; i < NGRAPH; i += HTHREADS) {
        histT[i * NCHUNK + blockIdx.x] = lh[i];
        if (lc[i]) atomicAdd(&cnt[i], lc[i]);
    }
}

// ---------------------------------------------------------------------------
// Kernel B: scan. Wave-parallel per-graph chunk prefix + 512-wide graph scan.
// ---------------------------------------------------------------------------
__global__ __launch_bounds__(1024) void scan_kernel(
    const int* __restrict__ histT,    // [NGRAPH*NCHUNK]
    int* __restrict__ baseT,          // [NGRAPH*NCHUNK] relative prefixes
    int* __restrict__ off,            // [NGRAPH+1]
    int E)
{
    __shared__ int tot[NGRAPH];
    const int t    = threadIdx.x;
    const int wave = t >> 6;
    const int lane = t & 63;

    for (int g = wave; g < NGRAPH; g += 16) {
        const int4 v = ((const int4*)(histT + g * NCHUNK))[lane];
        const int s0 = v.x;
        const int s1 = s0 + v.y;
        const int s2 = s1 + v.z;
        const int s3 = s2 + v.w;
        int p = s3;
        #pragma unroll
        for (int d = 1; d < 64; d <<= 1) {
            const int u = __shfl_up(p, d, 64);
            if (lane >= d) p += u;
        }
        const int base = p - s3;
        int4 o;
        o.x = base;
        o.y = base + s0;
        o.z = base + s1;
        o.w = base + s2;
        ((int4*)(baseT + g * NCHUNK))[lane] = o;
        const int total = __shfl(p, 63, 64);
        if (lane == 0) tot[g] = total;
    }
    __syncthreads();

    for (int d = 1; d < NGRAPH; d <<= 1) {
        int add = 0;
        if (t < NGRAPH && t >= d) add = tot[t - d];
        __syncthreads();
        if (t < NGRAPH) tot[t] += add;
        __syncthreads();
    }
    if (t < NGRAPH) {
        off[t + 1] = tot[t];
        if (t == 0) off[0] = 0;
    }
}

// ---------------------------------------------------------------------------
// Kernel C: scatter into graph-contiguous order. LDS cursors only.
// ---------------------------------------------------------------------------
__global__ __launch_bounds__(HTHREADS) void scatter_kernel(
    const int* __restrict__ edge_index,
    const float* __restrict__ edge_attr,
    const unsigned short* __restrict__ g16,
    const int* __restrict__ baseT,
    const int* __restrict__ off,
    int E, int echunk,
    int2* __restrict__ ed)            // [E] packed (src, bits(w))
{
    __shared__ int lcur[NGRAPH];
    for (int i = threadIdx.x; i < NGRAPH; i += HTHREADS)
        lcur[i] = off[i] + baseT[i * NCHUNK + blockIdx.x];
    __syncthreads();

    const int lo = blockIdx.x * echunk;
    const int hi = min(E, lo + echunk);
    for (int e = lo + threadIdx.x; e < hi; e += HTHREADS) {
        const int g = g16[e];
        const int p = atomicAdd(&lcur[g], 1);
        ed[p] = make_int2(edge_index[e], __float_as_int(edge_attr[e]));
    }
}

// ---------------------------------------------------------------------------
// Kernel D: per-graph bf16 gather + register accumulate + fused mean/MLP head.
// Block = 1 graph, 16 waves; 8 edge-groups x 8 feature-lanes per wave.
// ---------------------------------------------------------------------------
__global__ __launch_bounds__(ATHREADS) void aggregate_mlp_kernel(
    const int2* __restrict__ ed,
    const int* __restrict__ off,
    const unsigned short* __restrict__ xb,   // [N*DF] bf16
    const int* __restrict__ cnt,             // [NGRAPH]
    const float* __restrict__ W1,            // [DF*DHID]
    const float* __restrict__ b1,            // [DHID]
    const float* __restrict__ W2,            // [DHID]
    const float* __restrict__ b2,            // [1]
    float* __restrict__ out)                 // [NGRAPH]
{
    __shared__ float sW1[DF * DHID];
    for (int i = threadIdx.x; i < DF * DHID; i += ATHREADS) sW1[i] = W1[i];

    const int g     = blockIdx.x;
    const int start = off[g];
    const int end   = off[g + 1];
    const int wave  = threadIdx.x >> 6;
    const int lane  = threadIdx.x & 63;
    const int eg    = lane >> 3;
    const int fc    = lane & 7;

    float acc[12];
#pragma unroll
    for (int i = 0; i < 12; ++i) acc[i] = 0.f;

    int e = start + wave * 8 + eg;
    int2 sw = (e < end) ? ed[e] : make_int2(0, 0);
    while (e < end) {
        const int en = e + (ATHREADS / 8);
        const int2 swn = (en < end) ? ed[en] : make_int2(0, 0);

        const float w = __int_as_float(sw.y);
        // row: 96 bf16 = 24 x ushort4 (8B each); lane fc covers chunks fc+8c
        const ushort4* __restrict__ row = (const ushort4*)xb + (size_t)sw.x * 24;
#pragma unroll
        for (int c = 0; c < 3; ++c) {
            const ushort4 v = row[fc + c * 8];
            acc[c * 4 + 0] += w * bf2f(v.x);
            acc[c * 4 + 1] += w * bf2f(v.y);
            acc[c * 4 + 2] += w * bf2f(v.z);
            acc[c * 4 + 3] += w * bf2f(v.w);
        }
        e = en; sw = swn;
    }

#pragma unroll
    for (int m = 8; m <= 32; m <<= 1) {
#pragma unroll
        for (int i = 0; i < 12; ++i) acc[i] += __shfl_xor(acc[i], m, 64);
    }

    __shared__ float sh[ATHREADS / 64][DF];
    if (eg == 0) {
#pragma unroll
        for (int c = 0; c < 3; ++c)
#pragma unroll
            for (int k = 0; k < 4; ++k)
                sh[wave][c * 32 + fc * 4 + k] = acc[c * 4 + k];
    }
    __syncthreads();

    __shared__ float fin[DF];
    if (threadIdx.x < DF) {
        float s = 0.f;
#pragma unroll
        for (int wv = 0; wv < ATHREADS / 64; ++wv) s += sh[wv][threadIdx.x];
        const float inv = 1.f / fmaxf((float)cnt[g], 1.f);
        fin[threadIdx.x] = fmaxf(s * inv, 0.f);       // relu(pooled)
    }
    __syncthreads();

    if (threadIdx.x < 16) {
        float v = 0.f;
        if (threadIdx.x < DHID) {
            float h = b1[threadIdx.x];
            for (int f = 0; f < DF; ++f)
                h += fin[f] * sW1[f * DHID + threadIdx.x];
            v = fmaxf(h, 0.f) * W2[threadIdx.x];
        }
#pragma unroll
        for (int m = 1; m < 16; m <<= 1) v += __shfl_xor(v, m, 16);
        if (threadIdx.x == 0) out[g] = v + b2[0];
    }
}

// ---------------------------------------------------------------------------
extern "C" void kernel_launch(void* const* d_in, const int* in_sizes, int n_in,
                              void* d_out, int out_size, void* d_ws, size_t ws_size,
                              hipStream_t stream) {
    const float* x          = (const float*)d_in[0];
    const int*   edge_index = (const int*)  d_in[1];
    const float* edge_attr  = (const float*)d_in[2];
    const int*   batch      = (const int*)  d_in[3];
    const float* W1         = (const float*)d_in[4];
    const float* b1         = (const float*)d_in[5];
    const float* W2         = (const float*)d_in[6];
    const float* b2         = (const float*)d_in[7];

    const int E = in_sizes[1] / 2;   // 800000
    const int N = in_sizes[3];       // 50000
    const int echunk = (E + NCHUNK - 1) / NCHUNK;
    const int nchunk = (N + NCHUNK - 1) / NCHUNK;

    // workspace layout
    char* ws = (char*)d_ws;
    int2*           ed  = (int2*)ws;                                   // 8*E
    unsigned short* g16 = (unsigned short*)(ws + (size_t)8 * E);       // 2*E
    unsigned short* xb  = (unsigned short*)(ws + (size_t)10 * E);      // 2*N*DF
    char* tail = ws + (size_t)10 * E + (size_t)2 * N * DF;
    tail = (char*)(((size_t)tail + 255) & ~(size_t)255);
    int*   histT = (int*)tail;                        // NGRAPH*NCHUNK
    int*   baseT = histT + NGRAPH * NCHUNK;           // NGRAPH*NCHUNK
    int*   off   = baseT + NGRAPH * NCHUNK;           // NGRAPH+1
    int*   cnt   = off + NGRAPH + 2;                  // NGRAPH

    hipMemsetAsync(cnt, 0, NGRAPH * sizeof(int), stream);

    prep_kernel<<<NCHUNK, HTHREADS, 0, stream>>>(edge_index, batch, x, E, N,
                                                 echunk, nchunk, histT, g16,
                                                 xb, cnt);
    scan_kernel<<<1, 1024, 0, stream>>>(histT, baseT, off, E);
    scatter_kernel<<<NCHUNK, HTHREADS, 0, stream>>>(edge_index, edge_attr, g16,
                                                    baseT, off, E, echunk, ed);
    aggregate_mlp_kernel<<<NGRAPH, ATHREADS, 0, stream>>>(
        ed, off, xb, cnt, W1, b1, W2, b2, (float*)d_out);
}